// Round 9
// baseline (382.310 us; speedup 1.0000x reference)
//
#include <hip/hip_runtime.h>
#include <math.h>

// Problem constants (from reference setup_inputs)
#define Bb 8
#define Cc 24
#define Hh 320
#define Ww 640
#define HWp (Hh * Ww)        // 204800
#define NPIX (Bb * HWp)      // 1638400
#define PIX_PER_THREAD 4
#define NXCD 8
#define BLOCKS_PER_XCD 200   // grid 1600 = 8 * 200; 200 blocks = exactly one b

// Native clang vector type: __builtin_nontemporal_load/store require a
// pointer to scalar-or-vector-of-scalar, not HIP's struct vector types.
typedef float f4 __attribute__((ext_vector_type(4)));

// v9 = v8b + XCD-dense block swizzle (T1).
// Evidence chain: FETCH_SIZE == 153,600 KB == cost exactly -> disp is 100%
// L3-served, cost 100% cold-fetched each dispatch; the whole problem is
// streaming 157MB of cost at 1.6-1.8 TB/s vs 6.3 TB/s copy-rate. Falsified:
// MLP (v4), occupancy/VGPR, gather (v6), run length (v7), logical volume
// (v6), L3-alloc churn (v8b: nt gave +17%, partial). Remaining structural
// difference vs a copy: default bid%8 round-robin gives each XCD's L2 an
// every-8th-4KB comb over 24 planes (4KB run / 28KB gap) -> no dense fill
// stream per L2. Fix: vbid = (bid&7)*200 + (bid>>3). XCD k then owns the
// contiguous pixel range of batch b=k (200 blocks x 1024 px == HWp): each
// XCD cold-fetches a disjoint dense 19.66MB slab, 800KB-dense per c-step.
// Math identical to v8b (dv-carry, strict '>' ascending, nt cost/stores).
__global__ __launch_bounds__(256) void sparse_regression_kernel(
    const float* __restrict__ cost,
    const float* __restrict__ disp,
    float* __restrict__ pred,   // [B,H,W]   = NPIX floats
    float* __restrict__ prob)   // [B,2,H,W] = 2*NPIX floats
{
    // XCD-dense remap: consecutive hardware blocks round-robin across XCDs
    // (bid%8 = XCD), so give XCD k the contiguous block range [k*200,(k+1)*200).
    const int bid  = blockIdx.x;
    const int vbid = (bid & (NXCD - 1)) * BLOCKS_PER_XCD + (bid >> 3);

    const int t  = vbid * blockDim.x + threadIdx.x;
    const int p0 = t * PIX_PER_THREAD;

    const int b = p0 / HWp;          // == bid&7 under this mapping
    const int q = p0 - b * HWp;      // h*W + w

    const size_t base = (size_t)b * Cc * HWp + q;
    const float* cbase = cost + base;
    const float* dbase = disp + base;

    float m1[PIX_PER_THREAD], m2[PIX_PER_THREAD];
    float dv1[PIX_PER_THREAD], dv2[PIX_PER_THREAD];
#pragma unroll
    for (int j = 0; j < PIX_PER_THREAD; ++j) {
        m1[j] = -INFINITY; m2[j] = -INFINITY;
        dv1[j] = 0.0f;     dv2[j] = 0.0f;
    }

    // Streaming top-2 over channels, carrying disparity values.
    // cost: non-temporal (no cache alloc). disp: cached (proven L3-resident).
#pragma unroll
    for (int c = 0; c < Cc; ++c) {
        const f4 cv = __builtin_nontemporal_load(
            (const f4*)(cbase + (size_t)c * HWp));
        const f4 dv = *(const f4*)(dbase + (size_t)c * HWp);
#pragma unroll
        for (int j = 0; j < PIX_PER_THREAD; ++j) {
            const float val = cv[j];
            const float dvl = dv[j];
            const bool gt1 = val > m1[j];
            const bool gt2 = val > m2[j];
            m2[j]  = gt1 ? m1[j]  : (gt2 ? val : m2[j]);
            dv2[j] = gt1 ? dv1[j] : (gt2 ? dvl : dv2[j]);
            m1[j]  = gt1 ? val    : m1[j];
            dv1[j] = gt1 ? dvl    : dv1[j];
        }
    }

    f4 predo, p1o, p2o;
#pragma unroll
    for (int j = 0; j < PIX_PER_THREAD; ++j) {
        // softmax over {m1, m2}: p1 = 1/(1+exp(m2-m1)), m2-m1 <= 0
        const float e  = __expf(m2[j] - m1[j]);
        const float p1 = 1.0f / (1.0f + e);
        const float p2 = 1.0f - p1;
        predo[j] = dv1[j] * p1 + dv2[j] * p2;
        p1o[j] = p1;
        p2o[j] = p2;
    }

    // Coalesced non-temporal float4 stores (outputs never re-read here).
    __builtin_nontemporal_store(predo, (f4*)(pred + p0));
    float* pb = prob + (size_t)b * 2 * HWp + q;
    __builtin_nontemporal_store(p1o, (f4*)(pb));
    __builtin_nontemporal_store(p2o, (f4*)(pb + HWp));
}

extern "C" void kernel_launch(void* const* d_in, const int* in_sizes, int n_in,
                              void* d_out, int out_size, void* d_ws, size_t ws_size,
                              hipStream_t stream) {
    const float* cost = (const float*)d_in[0];
    const float* disp = (const float*)d_in[1];
    float* pred = (float*)d_out;          // first NPIX floats
    float* prob = (float*)d_out + NPIX;   // next 2*NPIX floats

    const int threads = NPIX / PIX_PER_THREAD;   // 409600
    const int block = 256;
    const int grid = (threads + block - 1) / block;  // 1600 = 8*200, exact
    sparse_regression_kernel<<<grid, block, 0, stream>>>(cost, disp, pred, prob);
}

// Round 10
// 314.905 us; speedup vs baseline: 1.2141x; 1.2141x over previous
//
#include <hip/hip_runtime.h>
#include <math.h>

// Problem constants (from reference setup_inputs)
#define Bb 8
#define Cc 24
#define Hh 320
#define Ww 640
#define HWp (Hh * Ww)        // 204800
#define NPIX (Bb * HWp)      // 1638400
#define PIX_PER_THREAD 4
#define NXCD 8
#define BLOCKS_PER_XCD 200   // grid 1600 = 8 * 200; 200 blocks = exactly one b

// Native clang vector type: __builtin_nontemporal_load/store require a
// pointer to scalar-or-vector-of-scalar, not HIP's struct vector types.
typedef float f4 __attribute__((ext_vector_type(4)));

// v10 = v9 (XCD-dense swizzle) with codegen PINNED.
// v9's test was confounded: dropping the bounds check let the compiler hoist
// loads into 160 VGPRs -> occupancy 10% -> 1.0 TB/s explained by occupancy
// alone, swizzle untested. v10 restores the guard (v8b's CFG) and adds
// __launch_bounds__(256, 8): min 8 waves/EU = 32 waves/CU -> allocator must
// stay <=64 VGPR (v8b used 28; no spill risk).
// Swizzle: bid%8 = XCD (round-robin dispatch), so vbid=(bid&7)*200+(bid>>3)
// hands XCD k the contiguous block range of batch b=k. Since b is the
// OUTERMOST dim of cost[b][c][h][w], XCD k cold-streams one contiguous
// 19.66 MB region — the maximally dense per-L2 fill stream (T1 mechanism).
// Math identical to v8b (dv-carry, strict '>' ascending, nt cost + stores,
// cached disp — FETCH==cost proves disp is 100% L3-served).
__global__ __launch_bounds__(256, 8) void sparse_regression_kernel(
    const float* __restrict__ cost,
    const float* __restrict__ disp,
    float* __restrict__ pred,   // [B,H,W]   = NPIX floats
    float* __restrict__ prob)   // [B,2,H,W] = 2*NPIX floats
{
    // XCD-dense remap.
    const int bid  = blockIdx.x;
    const int vbid = (bid & (NXCD - 1)) * BLOCKS_PER_XCD + (bid >> 3);

    const int t  = vbid * blockDim.x + threadIdx.x;
    const int p0 = t * PIX_PER_THREAD;
    if (p0 >= NPIX) return;   // never taken (grid exact) but pins the CFG/codegen

    const int b = p0 / HWp;          // == bid&7 under this mapping
    const int q = p0 - b * HWp;      // h*W + w

    const size_t base = (size_t)b * Cc * HWp + q;
    const float* cbase = cost + base;
    const float* dbase = disp + base;

    float m1[PIX_PER_THREAD], m2[PIX_PER_THREAD];
    float dv1[PIX_PER_THREAD], dv2[PIX_PER_THREAD];
#pragma unroll
    for (int j = 0; j < PIX_PER_THREAD; ++j) {
        m1[j] = -INFINITY; m2[j] = -INFINITY;
        dv1[j] = 0.0f;     dv2[j] = 0.0f;
    }

    // Streaming top-2 over channels, carrying disparity values.
    // cost: non-temporal (no cache alloc). disp: cached (proven L3-resident).
#pragma unroll
    for (int c = 0; c < Cc; ++c) {
        const f4 cv = __builtin_nontemporal_load(
            (const f4*)(cbase + (size_t)c * HWp));
        const f4 dv = *(const f4*)(dbase + (size_t)c * HWp);
#pragma unroll
        for (int j = 0; j < PIX_PER_THREAD; ++j) {
            const float val = cv[j];
            const float dvl = dv[j];
            const bool gt1 = val > m1[j];
            const bool gt2 = val > m2[j];
            m2[j]  = gt1 ? m1[j]  : (gt2 ? val : m2[j]);
            dv2[j] = gt1 ? dv1[j] : (gt2 ? dvl : dv2[j]);
            m1[j]  = gt1 ? val    : m1[j];
            dv1[j] = gt1 ? dvl    : dv1[j];
        }
    }

    f4 predo, p1o, p2o;
#pragma unroll
    for (int j = 0; j < PIX_PER_THREAD; ++j) {
        // softmax over {m1, m2}: p1 = 1/(1+exp(m2-m1)), m2-m1 <= 0
        const float e  = __expf(m2[j] - m1[j]);
        const float p1 = 1.0f / (1.0f + e);
        const float p2 = 1.0f - p1;
        predo[j] = dv1[j] * p1 + dv2[j] * p2;
        p1o[j] = p1;
        p2o[j] = p2;
    }

    // Coalesced non-temporal float4 stores (outputs never re-read here).
    __builtin_nontemporal_store(predo, (f4*)(pred + p0));
    float* pb = prob + (size_t)b * 2 * HWp + q;
    __builtin_nontemporal_store(p1o, (f4*)(pb));
    __builtin_nontemporal_store(p2o, (f4*)(pb + HWp));
}

extern "C" void kernel_launch(void* const* d_in, const int* in_sizes, int n_in,
                              void* d_out, int out_size, void* d_ws, size_t ws_size,
                              hipStream_t stream) {
    const float* cost = (const float*)d_in[0];
    const float* disp = (const float*)d_in[1];
    float* pred = (float*)d_out;          // first NPIX floats
    float* prob = (float*)d_out + NPIX;   // next 2*NPIX floats

    const int threads = NPIX / PIX_PER_THREAD;   // 409600
    const int block = 256;
    const int grid = (threads + block - 1) / block;  // 1600 = 8*200, exact
    sparse_regression_kernel<<<grid, block, 0, stream>>>(cost, disp, pred, prob);
}